// Round 1
// baseline (17724.290 us; speedup 1.0000x reference)
//
#include <hip/hip_runtime.h>

// Problem constants
#define NB   4
#define CIN  64
#define COUT 128
#define SDIM 512
#define DIM  48
#define SP   (DIM*DIM*DIM)   // 110592
#define TAPS 27

// Workspace layout (float offsets). Total = 905984 floats = 3.62 MB.
#define WS_S1P 0                        // [NB*CIN]      1+scale
#define WS_SH  (NB*CIN)                 // [NB*CIN]      shift
#define WS_KM  (WS_SH + NB*CIN)         // [NB*CIN*TAPS] kmod
#define WS_WT  (WS_KM + NB*CIN*TAPS)    // [NB*COUT*TAPS] shift-folded boundary term
#define WS_WSC (WS_WT + NB*COUT*TAPS)   // [NB*COUT*CIN*TAPS] fully modulated+scaled weights

// ---------------------------------------------------------------------------
// Kernel A: all style-modulation dot products. One wave (64 lanes) per output
// row; rows: [0,64)=scale, [64,128)=shift, [128,1856)=kmod, per sample b.
// ---------------------------------------------------------------------------
__global__ void modparams_kernel(const float* __restrict__ style,
                                 const float* __restrict__ w_scale, const float* __restrict__ b_scale,
                                 const float* __restrict__ w_shift, const float* __restrict__ b_shift,
                                 const float* __restrict__ w_kmod,  const float* __restrict__ b_kmod,
                                 float* __restrict__ ws) {
    const int ROWS = 2 * CIN + CIN * TAPS;  // 1856
    int gwave = (blockIdx.x * blockDim.x + threadIdx.x) >> 6;
    int lane  = threadIdx.x & 63;
    if (gwave >= NB * ROWS) return;
    int b = gwave / ROWS;
    int r = gwave % ROWS;

    const float* srow = style + b * SDIM;
    const float* mrow;
    float bias, add = 0.f;
    float* dst;
    if (r < CIN) {
        mrow = w_scale + r * SDIM; bias = b_scale[r];
        dst = ws + WS_S1P + b * CIN + r; add = 1.f;          // store (1+scale)
    } else if (r < 2 * CIN) {
        int c = r - CIN;
        mrow = w_shift + c * SDIM; bias = b_shift[c];
        dst = ws + WS_SH + b * CIN + c;
    } else {
        int t = r - 2 * CIN;
        mrow = w_kmod + t * SDIM; bias = b_kmod[t];
        dst = ws + WS_KM + b * (CIN * TAPS) + t;
    }

    float acc = 0.f;
    for (int k = lane; k < SDIM; k += 64) acc += srow[k] * mrow[k];
    #pragma unroll
    for (int off = 32; off; off >>= 1) acc += __shfl_down(acc, off);
    if (lane == 0) *dst = acc + bias + add;
}

// ---------------------------------------------------------------------------
// Kernel B: WS[b,o,c,tau] = weight[o,c,tau] * (1+kmod[b,c,tau]) * (1+scale[b,c])
// ---------------------------------------------------------------------------
__global__ void build_ws_kernel(const float* __restrict__ weight, float* __restrict__ ws) {
    const float* s1p = ws + WS_S1P;
    const float* km  = ws + WS_KM;
    float* WS = ws + WS_WSC;
    int idx = blockIdx.x * blockDim.x + threadIdx.x;
    if (idx >= NB * COUT * CIN * TAPS) return;
    int t = idx % (CIN * TAPS);              // c*27+tau
    int o = (idx / (CIN * TAPS)) % COUT;
    int b = idx / (COUT * CIN * TAPS);
    int c = t / TAPS;
    float wm = weight[o * (CIN * TAPS) + t] * (1.f + km[b * (CIN * TAPS) + t]);
    WS[idx] = wm * s1p[b * CIN + c];
}

// ---------------------------------------------------------------------------
// Kernel B2: WT[b,o,tau] = sum_c weight[o,c,tau]*(1+kmod[b,c,tau]) * shift[b,c]
// ---------------------------------------------------------------------------
__global__ void build_wt_kernel(const float* __restrict__ weight, float* __restrict__ ws) {
    const float* sh = ws + WS_SH;
    const float* km = ws + WS_KM;
    float* WT = ws + WS_WT;
    int idx = blockIdx.x * blockDim.x + threadIdx.x;
    if (idx >= NB * COUT * TAPS) return;
    int tau = idx % TAPS;
    int o   = (idx / TAPS) % COUT;
    int b   = idx / (COUT * TAPS);
    float acc = 0.f;
    for (int c = 0; c < CIN; ++c) {
        float wm = weight[(o * CIN + c) * TAPS + tau] * (1.f + km[(b * CIN + c) * TAPS + tau]);
        acc += wm * sh[b * CIN + c];
    }
    WT[idx] = acc;
}

// ---------------------------------------------------------------------------
// Conv kernel: direct 3D conv with per-(b,o) weights WS (zero-padded x) plus
// per-position boundary correction from WT and bias.
// Block = 256 threads; each thread computes 4 consecutive-w outputs.
// Grid = NB * COUT * (SP/1024) = 4*128*108.
// ---------------------------------------------------------------------------
#define CHUNKS (SP / 1024)   // 108

__global__ __launch_bounds__(256) void conv_kernel(const float* __restrict__ x,
                                                   const float* __restrict__ bias,
                                                   const float* __restrict__ ws,
                                                   float* __restrict__ out) {
    const float* WT = ws + WS_WT;
    const float* WS = ws + WS_WSC;

    int bid   = blockIdx.x;
    int chunk = bid % CHUNKS;
    int o     = (bid / CHUNKS) % COUT;
    int b     = bid / (CHUNKS * COUT);

    __shared__ float lw[CIN * 28];   // row-padded to 28 for aligned float4 reads
    __shared__ float lwt[TAPS];
    __shared__ float lbias;

    const float* wsrc = WS + (b * COUT + o) * (CIN * TAPS);
    for (int i = threadIdx.x; i < CIN * TAPS; i += 256) {
        int c = i / TAPS, t = i - c * TAPS;
        lw[c * 28 + t] = wsrc[i];
    }
    if (threadIdx.x < TAPS) lwt[threadIdx.x] = WT[(b * COUT + o) * TAPS + threadIdx.x];
    if (threadIdx.x == 0) lbias = bias[o];
    __syncthreads();

    int idx = chunk * 256 + threadIdx.x;  // 4-output group id
    int p0  = idx * 4;
    int w0  = p0 % DIM;                   // multiple of 4 (48%4==0)
    int h   = (p0 / DIM) % DIM;
    int d   = p0 / (DIM * DIM);

    const float* xb = x + b * (CIN * SP);
    float acc0 = 0.f, acc1 = 0.f, acc2 = 0.f, acc3 = 0.f;

    for (int c = 0; c < CIN; ++c) {
        // weights for this cin -> registers (broadcast LDS reads)
        float wr[28];
        const float4* lw4 = (const float4*)(lw + c * 28);
        #pragma unroll
        for (int i = 0; i < 7; ++i) {
            float4 v = lw4[i];
            wr[4*i] = v.x; wr[4*i+1] = v.y; wr[4*i+2] = v.z; wr[4*i+3] = v.w;
        }
        const float* xc = xb + c * SP;
        #pragma unroll
        for (int kd = 0; kd < 3; ++kd) {
            int zd = d + kd - 1;
            bool dok = (unsigned)zd < (unsigned)DIM;
            #pragma unroll
            for (int kh = 0; kh < 3; ++kh) {
                int zh = h + kh - 1;
                bool hok = (unsigned)zh < (unsigned)DIM;
                if (dok && hok) {
                    const float* row = xc + zd * (DIM * DIM) + zh * DIM;
                    float4 m = *(const float4*)(row + w0);
                    float xl = (w0 > 0)        ? row[w0 - 1] : 0.f;
                    float xr = (w0 + 4 < DIM)  ? row[w0 + 4] : 0.f;
                    float xv[6] = {xl, m.x, m.y, m.z, m.w, xr};
                    const float* wp = wr + (kd * 3 + kh) * 3;
                    #pragma unroll
                    for (int kw = 0; kw < 3; ++kw) {
                        float wv = wp[kw];
                        acc0 += wv * xv[kw];
                        acc1 += wv * xv[kw + 1];
                        acc2 += wv * xv[kw + 2];
                        acc3 += wv * xv[kw + 3];
                    }
                }
            }
        }
    }

    // boundary correction (shift term counts only in-bounds taps) + bias
    float bb = lbias;
    #pragma unroll
    for (int kd = 0; kd < 3; ++kd) {
        bool dok = (unsigned)(d + kd - 1) < (unsigned)DIM;
        #pragma unroll
        for (int kh = 0; kh < 3; ++kh) {
            bool hok = (unsigned)(h + kh - 1) < (unsigned)DIM;
            bool dh = dok && hok;
            #pragma unroll
            for (int kw = 0; kw < 3; ++kw) {
                float wt = lwt[kd * 9 + kh * 3 + kw];
                acc0 += (dh && (unsigned)(w0 + 0 + kw - 1) < (unsigned)DIM) ? wt : 0.f;
                acc1 += (dh && (unsigned)(w0 + 1 + kw - 1) < (unsigned)DIM) ? wt : 0.f;
                acc2 += (dh && (unsigned)(w0 + 2 + kw - 1) < (unsigned)DIM) ? wt : 0.f;
                acc3 += (dh && (unsigned)(w0 + 3 + kw - 1) < (unsigned)DIM) ? wt : 0.f;
            }
        }
    }

    float4 r;
    r.x = acc0 + bb; r.y = acc1 + bb; r.z = acc2 + bb; r.w = acc3 + bb;
    *(float4*)(out + (b * COUT + o) * SP + p0) = r;
}

// ---------------------------------------------------------------------------
extern "C" void kernel_launch(void* const* d_in, const int* in_sizes, int n_in,
                              void* d_out, int out_size, void* d_ws, size_t ws_size,
                              hipStream_t stream) {
    const float* x       = (const float*)d_in[0];
    const float* style   = (const float*)d_in[1];
    const float* weight  = (const float*)d_in[2];
    const float* bias    = (const float*)d_in[3];
    const float* w_scale = (const float*)d_in[4];
    const float* b_scale = (const float*)d_in[5];
    const float* w_shift = (const float*)d_in[6];
    const float* b_shift = (const float*)d_in[7];
    const float* w_kmod  = (const float*)d_in[8];
    const float* b_kmod  = (const float*)d_in[9];
    float* out = (float*)d_out;
    float* ws  = (float*)d_ws;

    // A: style dots. NB*1856 waves, 4 waves/block.
    {
        int waves = NB * (2 * CIN + CIN * TAPS);
        int blocks = (waves + 3) / 4;
        modparams_kernel<<<blocks, 256, 0, stream>>>(style, w_scale, b_scale,
                                                     w_shift, b_shift, w_kmod, b_kmod, ws);
    }
    // B: modulated+scaled weights
    {
        int n = NB * COUT * CIN * TAPS;
        build_ws_kernel<<<(n + 255) / 256, 256, 0, stream>>>(weight, ws);
    }
    // B2: shift-folded boundary weights
    {
        int n = NB * COUT * TAPS;
        build_wt_kernel<<<(n + 255) / 256, 256, 0, stream>>>(weight, ws);
    }
    // C: conv
    {
        int blocks = NB * COUT * CHUNKS;
        conv_kernel<<<blocks, 256, 0, stream>>>(x, bias, ws, out);
    }
}

// Round 2
// 606.188 us; speedup vs baseline: 29.2389x; 29.2389x over previous
//
#include <hip/hip_runtime.h>
#include <hip/hip_bf16.h>

// Problem constants
#define NB   4
#define CIN  64
#define COUT 128
#define SDIM 512
#define DIM  48
#define SP   (DIM*DIM*DIM)   // 110592
#define TAPS 27
#define KTOT (CIN*TAPS)      // 1728

// Workspace layout (float offsets)
#define WS_S1P 0                         // [NB*CIN]       1+scale
#define WS_SH  (WS_S1P + NB*CIN)         // [NB*CIN]       shift
#define WS_KM  (WS_SH + NB*CIN)          // [NB*CIN*TAPS]  kmod
#define WS_WT  (WS_KM + NB*CIN*TAPS)     // [NB*COUT*TAPS] shift-folded boundary term
#define WS_WTF (WS_WT + NB*COUT*TAPS)    // [NB*COUT]      full-sum of WT
#define WS_WSB (WS_WTF + NB*COUT)        // [NB*COUT*KTOT] bf16 weights, k = tau*64+c

typedef __attribute__((ext_vector_type(4))) float  f32x4;
typedef __attribute__((ext_vector_type(8))) short  short8;
typedef __attribute__((ext_vector_type(8))) unsigned short u16x8;

// ---------------------------------------------------------------------------
// Kernel A: style dot products. One wave per row.
// rows: [0,64)=scale, [64,128)=shift, [128,1856)=kmod, per sample b.
// ---------------------------------------------------------------------------
__global__ void modparams_kernel(const float* __restrict__ style,
                                 const float* __restrict__ w_scale, const float* __restrict__ b_scale,
                                 const float* __restrict__ w_shift, const float* __restrict__ b_shift,
                                 const float* __restrict__ w_kmod,  const float* __restrict__ b_kmod,
                                 float* __restrict__ ws) {
    const int ROWS = 2 * CIN + CIN * TAPS;  // 1856
    int gwave = (blockIdx.x * blockDim.x + threadIdx.x) >> 6;
    int lane  = threadIdx.x & 63;
    if (gwave >= NB * ROWS) return;
    int b = gwave / ROWS;
    int r = gwave % ROWS;

    const float* srow = style + b * SDIM;
    const float* mrow;
    float bias, add = 0.f;
    float* dst;
    if (r < CIN) {
        mrow = w_scale + r * SDIM; bias = b_scale[r];
        dst = ws + WS_S1P + b * CIN + r; add = 1.f;          // store (1+scale)
    } else if (r < 2 * CIN) {
        int c = r - CIN;
        mrow = w_shift + c * SDIM; bias = b_shift[c];
        dst = ws + WS_SH + b * CIN + c;
    } else {
        int t = r - 2 * CIN;
        mrow = w_kmod + t * SDIM; bias = b_kmod[t];
        dst = ws + WS_KM + b * (CIN * TAPS) + t;
    }

    float acc = 0.f;
    for (int k = lane; k < SDIM; k += 64) acc += srow[k] * mrow[k];
    #pragma unroll
    for (int off = 32; off; off >>= 1) acc += __shfl_down(acc, off);
    if (lane == 0) *dst = acc + bias + add;
}

// ---------------------------------------------------------------------------
// Kernel B: WSB[b][o][tau*64+c] = bf16( weight[o,c,tau]*(1+kmod[b,c,tau])*(1+scale[b,c]) )
// ---------------------------------------------------------------------------
__global__ void build_wsb_kernel(const float* __restrict__ weight, float* __restrict__ ws) {
    const float* s1p = ws + WS_S1P;
    const float* km  = ws + WS_KM;
    unsigned short* WSB = (unsigned short*)(ws + WS_WSB);
    int idx = blockIdx.x * blockDim.x + threadIdx.x;
    if (idx >= NB * COUT * KTOT) return;
    int k = idx % KTOT;
    int o = (idx / KTOT) % COUT;
    int b = idx / (COUT * KTOT);
    int tau = k >> 6;
    int c   = k & 63;
    float wm = weight[(o * CIN + c) * TAPS + tau] * (1.f + km[b * (CIN * TAPS) + c * TAPS + tau]);
    float v  = wm * s1p[b * CIN + c];
    __hip_bfloat16 h = __float2bfloat16(v);
    WSB[idx] = *(unsigned short*)&h;
}

// ---------------------------------------------------------------------------
// Kernel B2: WT[b,o,tau] = sum_c weight[o,c,tau]*(1+kmod[b,c,tau]) * shift[b,c]
// ---------------------------------------------------------------------------
__global__ void build_wt_kernel(const float* __restrict__ weight, float* __restrict__ ws) {
    const float* sh = ws + WS_SH;
    const float* km = ws + WS_KM;
    float* WT = ws + WS_WT;
    int idx = blockIdx.x * blockDim.x + threadIdx.x;
    if (idx >= NB * COUT * TAPS) return;
    int tau = idx % TAPS;
    int o   = (idx / TAPS) % COUT;
    int b   = idx / (COUT * TAPS);
    float acc = 0.f;
    for (int c = 0; c < CIN; ++c) {
        float wm = weight[(o * CIN + c) * TAPS + tau] * (1.f + km[(b * CIN + c) * TAPS + tau]);
        acc += wm * sh[b * CIN + c];
    }
    WT[idx] = acc;
}

// ---------------------------------------------------------------------------
// Kernel B3: WTF[b,o] = sum_tau WT[b,o,tau]
// ---------------------------------------------------------------------------
__global__ void build_wtf_kernel(float* __restrict__ ws) {
    int i = blockIdx.x * blockDim.x + threadIdx.x;
    if (i >= NB * COUT) return;
    const float* wt = ws + WS_WT + i * TAPS;
    float s = 0.f;
    #pragma unroll
    for (int t = 0; t < TAPS; ++t) s += wt[t];
    ws[WS_WTF + i] = s;
}

// ---------------------------------------------------------------------------
// Conv as implicit GEMM with MFMA.
// Per block: b sample, 128 contiguous flattened spatial positions (N-tile),
// all 128 couts (M). K = 1728 = 27 taps x 64 cin, BK=32 (tau fixed per step).
// LDS: At[m][k], Bt[n][k] bf16 rows of 32 elems, row stride 80B.
// 4 waves, each computes 64x64 (4x4 fragments of 16x16).
// ---------------------------------------------------------------------------
#define BN 128
#define NTILES (SP / BN)   // 864

__global__ __launch_bounds__(256) void conv_mfma_kernel(
    const float* __restrict__ x,
    const float* __restrict__ bias,
    const float* __restrict__ ws,
    float* __restrict__ out)
{
    const unsigned short* WSB = (const unsigned short*)(ws + WS_WSB);
    const float* WT  = ws + WS_WT;
    const float* WTF = ws + WS_WTF;

    __shared__ __attribute__((aligned(16))) unsigned short At[128 * 40]; // byte: m*80 + k*2
    __shared__ __attribute__((aligned(16))) unsigned short Bt[128 * 40]; // byte: n*80 + k*2
    __shared__ float WTl[128][28];   // [o][tau], slot 27 = full sum
    __shared__ float lbias[128];

    int bid  = blockIdx.x;
    int tile = bid % NTILES;
    int b    = bid / NTILES;
    int p0   = tile * BN;

    int t    = threadIdx.x;
    int lane = t & 63;
    int wid  = t >> 6;
    int wm   = (wid >> 1) * 64;   // wave M origin
    int wn   = (wid & 1) * 64;    // wave N origin

    f32x4 acc[4][4] = {};

    // B-staging mapping: thread owns column n, 16 k's (k = bch*16 + i)
    int bn  = t & 127;
    int bch = t >> 7;
    int p   = p0 + bn;
    int wq  = p % DIM;
    int hq  = (p / DIM) % DIM;
    int dq  = p / (DIM * DIM);

    // A-staging mapping: thread owns row am, k-chunk ak..ak+15
    int am = t >> 1;
    int ak = (t & 1) * 16;

    const float* xb = x + (size_t)b * CIN * SP;
    const unsigned short* wsbB = WSB + (size_t)(b * COUT + am) * KTOT;

    for (int kk = 0; kk < 54; ++kk) {
        int tau   = kk >> 1;
        int chalf = (kk & 1) * 32;
        int dz = tau / 9 - 1;
        int dy = (tau / 3) % 3 - 1;
        int dx = tau % 3 - 1;

        // ---- stage A: WSB[b][am][tau*64 + chalf + ak .. +16) ----
        {
            const u16x8* src = (const u16x8*)(wsbB + tau * 64 + chalf + ak);
            u16x8 a0 = src[0];
            u16x8 a1 = src[1];
            *(u16x8*)(&At[am * 40 + ak])     = a0;
            *(u16x8*)(&At[am * 40 + ak + 8]) = a1;
        }

        // ---- stage B: x[chalf + bch*16 + i][p + off] masked, -> bf16 ----
        {
            bool valid = ((unsigned)(dq + dz) < (unsigned)DIM) &&
                         ((unsigned)(hq + dy) < (unsigned)DIM) &&
                         ((unsigned)(wq + dx) < (unsigned)DIM);
            int off = dz * (DIM * DIM) + dy * DIM + dx;
            unsigned short v16[16];
            if (valid) {
                const float* src = xb + (size_t)(chalf + bch * 16) * SP + p + off;
                #pragma unroll
                for (int i = 0; i < 16; ++i) {
                    __hip_bfloat16 h = __float2bfloat16(src[0]);
                    v16[i] = *(unsigned short*)&h;
                    src += SP;
                }
            } else {
                #pragma unroll
                for (int i = 0; i < 16; ++i) v16[i] = 0;
            }
            u16x8* dst = (u16x8*)(&Bt[bn * 40 + bch * 16]);
            u16x8 pk0, pk1;
            #pragma unroll
            for (int i = 0; i < 8; ++i) { pk0[i] = v16[i]; pk1[i] = v16[i + 8]; }
            dst[0] = pk0;
            dst[1] = pk1;
        }

        __syncthreads();

        // ---- fragments + MFMA ----
        short8 af[4], bf[4];
        int arow = lane & 15;
        int kofs = (lane >> 4) * 8;    // elements; *2 bytes
        #pragma unroll
        for (int mf = 0; mf < 4; ++mf)
            af[mf] = *(const short8*)(&At[(wm + mf * 16 + arow) * 40 + kofs]);
        #pragma unroll
        for (int nf = 0; nf < 4; ++nf)
            bf[nf] = *(const short8*)(&Bt[(wn + nf * 16 + arow) * 40 + kofs]);
        #pragma unroll
        for (int mf = 0; mf < 4; ++mf)
            #pragma unroll
            for (int nf = 0; nf < 4; ++nf)
                acc[mf][nf] = __builtin_amdgcn_mfma_f32_16x16x32_bf16(af[mf], bf[nf], acc[mf][nf], 0, 0, 0);

        __syncthreads();
    }

    // ---- epilogue: bias + boundary correction (shift term), then store ----
    for (int i = t; i < 128 * 28; i += 256) {
        int o = i / 28, j = i - o * 28;
        WTl[o][j] = (j < 27) ? WT[(b * COUT + o) * TAPS + j] : WTF[b * COUT + o];
    }
    if (t < 128) lbias[t] = bias[t];
    __syncthreads();

    #pragma unroll
    for (int nf = 0; nf < 4; ++nf) {
        int n  = wn + nf * 16 + (lane & 15);
        int pc = p0 + n;
        int wq2 = pc % DIM;
        int hq2 = (pc / DIM) % DIM;
        int dq2 = pc / (DIM * DIM);
        bool interior = ((unsigned)(wq2 - 1) < (unsigned)(DIM - 2)) &&
                        ((unsigned)(hq2 - 1) < (unsigned)(DIM - 2)) &&
                        ((unsigned)(dq2 - 1) < (unsigned)(DIM - 2));
        bool mw[3] = { wq2 > 0, true, wq2 < DIM - 1 };
        bool mh[3] = { hq2 > 0, true, hq2 < DIM - 1 };
        bool md[3] = { dq2 > 0, true, dq2 < DIM - 1 };

        #pragma unroll
        for (int mf = 0; mf < 4; ++mf) {
            int ob = wm + mf * 16 + ((lane >> 4) << 2);
            f32x4 a = acc[mf][nf];
            #pragma unroll
            for (int r = 0; r < 4; ++r) {
                int o = ob + r;
                float v = a[r] + lbias[o];
                if (interior) {
                    v += WTl[o][27];
                } else {
                    const float* wt = WTl[o];
                    float s = 0.f;
                    #pragma unroll
                    for (int a3 = 0; a3 < 3; ++a3)
                        #pragma unroll
                        for (int b3 = 0; b3 < 3; ++b3)
                            #pragma unroll
                            for (int c3 = 0; c3 < 3; ++c3)
                                s += (md[a3] && mh[b3] && mw[c3]) ? wt[a3 * 9 + b3 * 3 + c3] : 0.f;
                    v += s;
                }
                out[(size_t)(b * COUT + o) * SP + pc] = v;
            }
        }
    }
}

// ---------------------------------------------------------------------------
extern "C" void kernel_launch(void* const* d_in, const int* in_sizes, int n_in,
                              void* d_out, int out_size, void* d_ws, size_t ws_size,
                              hipStream_t stream) {
    const float* x       = (const float*)d_in[0];
    const float* style   = (const float*)d_in[1];
    const float* weight  = (const float*)d_in[2];
    const float* bias    = (const float*)d_in[3];
    const float* w_scale = (const float*)d_in[4];
    const float* b_scale = (const float*)d_in[5];
    const float* w_shift = (const float*)d_in[6];
    const float* b_shift = (const float*)d_in[7];
    const float* w_kmod  = (const float*)d_in[8];
    const float* b_kmod  = (const float*)d_in[9];
    float* out = (float*)d_out;
    float* ws  = (float*)d_ws;

    {
        int waves = NB * (2 * CIN + CIN * TAPS);
        int blocks = (waves + 3) / 4;
        modparams_kernel<<<blocks, 256, 0, stream>>>(style, w_scale, b_scale,
                                                     w_shift, b_shift, w_kmod, b_kmod, ws);
    }
    {
        int n = NB * COUT * KTOT;
        build_wsb_kernel<<<(n + 255) / 256, 256, 0, stream>>>(weight, ws);
    }
    {
        int n = NB * COUT * TAPS;
        build_wt_kernel<<<(n + 255) / 256, 256, 0, stream>>>(weight, ws);
    }
    {
        int n = NB * COUT;
        build_wtf_kernel<<<(n + 255) / 256, 256, 0, stream>>>(ws);
    }
    {
        int blocks = NB * NTILES;
        conv_mfma_kernel<<<blocks, 256, 0, stream>>>(x, bias, ws, out);
    }
}

// Round 3
// 351.721 us; speedup vs baseline: 50.3931x; 1.7235x over previous
//
#include <hip/hip_runtime.h>
#include <hip/hip_bf16.h>

// Problem constants
#define NB   4
#define CIN  64
#define COUT 128
#define SDIM 512
#define DIM  48
#define SP   (DIM*DIM*DIM)   // 110592
#define TAPS 27
#define KTOT (CIN*TAPS)      // 1728

// ---- shared small-param layout (float offsets at base of ws), both paths ----
#define WS_S1P 0                         // [NB*CIN]       1+scale
#define WS_SH  (WS_S1P + NB*CIN)         // [NB*CIN]       shift
#define WS_KM  (WS_SH + NB*CIN)          // [NB*CIN*TAPS]  kmod
// ---- fallback(round-2) extras ----
#define WS_WT  (WS_KM + NB*CIN*TAPS)     // [NB*COUT*TAPS]
#define WS_WTF (WS_WT + NB*COUT*TAPS)    // [NB*COUT]
#define WS_WSB (WS_WTF + NB*COUT)        // [NB*COUT*KTOT] bf16 (old path)
// ---- fast path byte offsets ----
#define XPB_OFF   32768ull                        // padded mod x, 64 MB
#define XPB_BYTES (4ull*125000ull*64ull*2ull)     // 64,000,000
#define WSBF_OFF  (XPB_OFF + XPB_BYTES)
#define WSBF_BYTES ((size_t)NB*COUT*KTOT*2)       // 1,769,472
#define NEED_FAST (WSBF_OFF + WSBF_BYTES)

typedef __attribute__((ext_vector_type(4))) float  f32x4;
typedef __attribute__((ext_vector_type(8))) short  short8;
typedef __attribute__((ext_vector_type(8))) unsigned short u16x8;

__device__ __forceinline__ void gld16(const void* g, void* l) {
    __builtin_amdgcn_global_load_lds(
        (const __attribute__((address_space(1))) void*)g,
        (__attribute__((address_space(3))) void*)l, 16, 0, 0);
}

// ---------------------------------------------------------------------------
// Kernel A: style dot products. One wave per row. (shared by both paths)
// ---------------------------------------------------------------------------
__global__ void modparams_kernel(const float* __restrict__ style,
                                 const float* __restrict__ w_scale, const float* __restrict__ b_scale,
                                 const float* __restrict__ w_shift, const float* __restrict__ b_shift,
                                 const float* __restrict__ w_kmod,  const float* __restrict__ b_kmod,
                                 float* __restrict__ ws) {
    const int ROWS = 2 * CIN + CIN * TAPS;  // 1856
    int gwave = (blockIdx.x * blockDim.x + threadIdx.x) >> 6;
    int lane  = threadIdx.x & 63;
    if (gwave >= NB * ROWS) return;
    int b = gwave / ROWS;
    int r = gwave % ROWS;

    const float* srow = style + b * SDIM;
    const float* mrow;
    float bias, add = 0.f;
    float* dst;
    if (r < CIN) {
        mrow = w_scale + r * SDIM; bias = b_scale[r];
        dst = ws + WS_S1P + b * CIN + r; add = 1.f;          // store (1+scale)
    } else if (r < 2 * CIN) {
        int c = r - CIN;
        mrow = w_shift + c * SDIM; bias = b_shift[c];
        dst = ws + WS_SH + b * CIN + c;
    } else {
        int t = r - 2 * CIN;
        mrow = w_kmod + t * SDIM; bias = b_kmod[t];
        dst = ws + WS_KM + b * (CIN * TAPS) + t;
    }

    float acc = 0.f;
    for (int k = lane; k < SDIM; k += 64) acc += srow[k] * mrow[k];
    #pragma unroll
    for (int off = 32; off; off >>= 1) acc += __shfl_down(acc, off);
    if (lane == 0) *dst = acc + bias + add;
}

// ===========================================================================
// FAST PATH
// ===========================================================================

// WSBF[b][o][tau*64+c] = bf16( weight[o,c,tau] * (1+kmod[b,c,tau]) )  (no scale)
__global__ void build_wsbf_kernel(const float* __restrict__ weight, const float* __restrict__ ws,
                                  unsigned short* __restrict__ wsbf) {
    int idx = blockIdx.x * blockDim.x + threadIdx.x;
    if (idx >= NB * COUT * KTOT) return;
    int k = idx % KTOT;
    int o = (idx / KTOT) % COUT;
    int b = idx / (COUT * KTOT);
    int tau = k >> 6, c = k & 63;
    float wm = weight[(o * CIN + c) * TAPS + tau] * (1.f + ws[WS_KM + b * KTOT + c * TAPS + tau]);
    __hip_bfloat16 h = __float2bfloat16(wm);
    wsbf[idx] = *(unsigned short*)&h;
}

// Pad + modulate + transpose to channel-last bf16: xpb[b][pz][py][px][c]
// One block per (b, pz, py) padded row; 50 px x 64 c written coalesced.
__global__ __launch_bounds__(256) void pad_kernel(const float* __restrict__ x,
                                                  const float* __restrict__ ws,
                                                  unsigned short* __restrict__ xpb) {
    __shared__ unsigned short lxm[48 * 72];   // [w][c], row stride 144B (16B-aligned)
    int bid = blockIdx.x;
    int py = bid % 50;
    int pz = (bid / 50) % 50;
    int b  = bid / 2500;
    int t = threadIdx.x;
    bool interior = (pz >= 1 && pz <= 48 && py >= 1 && py <= 48);
    if (interior) {
        int z = pz - 1, y = py - 1;
        const float* xr = x + (size_t)b * CIN * SP + (size_t)z * (DIM*DIM) + y * DIM;
        for (int i = t; i < 3072; i += 256) {
            int c = i / 48, w = i % 48;
            float v = xr[(size_t)c * SP + w];
            float m = v * ws[WS_S1P + b * CIN + c] + ws[WS_SH + b * CIN + c];
            __hip_bfloat16 h = __float2bfloat16(m);
            lxm[w * 72 + c] = *(unsigned short*)&h;
        }
    }
    __syncthreads();
    unsigned short* dst = xpb + (size_t)b * 8000000ull + ((size_t)pz * 2500 + py * 50) * 64;
    // 3200 u16 = 400 vec8
    for (int i8 = t; i8 < 400; i8 += 256) {
        int w  = i8 >> 3;          // padded px
        int c8 = (i8 & 7) * 8;
        u16x8 v = {};
        if (interior && w >= 1 && w <= 48)
            v = *(const u16x8*)&lxm[(w - 1) * 72 + c8];
        *(u16x8*)(dst + i8 * 8) = v;
    }
}

// ---------------------------------------------------------------------------
// Fast conv: output box 4(z) x 4(y) x 8(w) = 128 positions, all 128 couts.
// B = halo tile 6x6x10 x 64c bf16 staged once (swizzled); A = per-tap 128x64
// weights double-buffered via global_load_lds. 4 waves, 64x64 each, 4x4 frags.
// ---------------------------------------------------------------------------
#define HZ 6
#define HY 6
#define HX 10
#define HPOS (HZ*HY*HX)      // 360
#define BCHUNK (HPOS*8)      // 2880 16B-chunks

__global__ __launch_bounds__(256, 2) void conv_fast_kernel(
    const unsigned short* __restrict__ xpb,
    const unsigned short* __restrict__ wsbf,
    const float* __restrict__ bias,
    float* __restrict__ out)
{
    __shared__ unsigned short Bh[HPOS * 64];     // 46080 B
    __shared__ unsigned short At[2][128 * 64];   // 2 x 16384 B
    __shared__ float lbias[128];

    const int t    = threadIdx.x;
    const int lane = t & 63;
    const int wid  = t >> 6;

    int bid  = blockIdx.x;
    int tile = bid % 864;
    int b    = bid / 864;
    int tx = tile % 6;
    int ty = (tile / 6) % 12;
    int tz = tile / 72;
    int x0 = tx * 8, y0 = ty * 4, z0 = tz * 4;

    const unsigned short* xb = xpb + (size_t)b * 8000000ull;
    const unsigned short* wb = wsbf + (size_t)b * (COUT * KTOT);

    // ---- stage B halo once (source-swizzled so linear LDS == swizzled layout)
    #pragma unroll
    for (int it = 0; it < 12; ++it) {
        int i = it * 256 + t;
        if (i < BCHUNK) {
            int pidx = i >> 3;
            int slot = i & 7;
            int hx  = pidx % 10;
            int hzy = pidx / 10;
            int hy  = hzy % 6;
            int hz  = hzy / 6;
            int srcslot = slot ^ (pidx & 7);
            const unsigned short* g = xb
                + ((size_t)((z0 + hz) * 2500 + (y0 + hy) * 50 + (x0 + hx))) * 64
                + srcslot * 8;
            gld16(g, &Bh[(size_t)i * 8]);
        }
    }
    // ---- stage A for tap 0 into buf 0 ----
    #pragma unroll
    for (int it = 0; it < 4; ++it) {
        int j = it * 256 + t;
        int o = j >> 3, slot = j & 7;
        int srcslot = slot ^ (o & 7);
        gld16(wb + (size_t)o * KTOT + 0 * 64 + srcslot * 8, &At[0][j * 8]);
    }
    if (t < 128) lbias[t] = bias[t];
    __syncthreads();

    // per-lane geometry
    int wm  = (wid >> 1) * 64;
    int wn  = (wid & 1) * 64;
    int col = lane & 15;
    int krow = lane >> 4;                 // 0..3
    int n0   = wn + col;
    int tzb0 = n0 >> 5;
    int tyb0 = (n0 >> 3) & 3;
    int twb  = n0 & 7;

    f32x4 acc[4][4] = {};
    int buf = 0;

    for (int tap = 0; tap < 27; ++tap) {
        // prefetch A for next tap
        if (tap < 26) {
            #pragma unroll
            for (int it = 0; it < 4; ++it) {
                int j = it * 256 + t;
                int o = j >> 3, slot = j & 7;
                int srcslot = slot ^ (o & 7);
                gld16(wb + (size_t)o * KTOT + (tap + 1) * 64 + srcslot * 8,
                      &At[buf ^ 1][j * 8]);
            }
        }

        int kd = tap / 9;
        int kh = (tap / 3) % 3;
        int kw = tap - kd * 9 - kh * 3;
        int pbase = ((tzb0 + kd) * 6 + (tyb0 + kh)) * 10 + twb + kw;  // nf=0 halo pos

        const unsigned short* Ab = &At[buf][0];
        #pragma unroll
        for (int ch = 0; ch < 2; ++ch) {
            int slot = ch * 4 + krow;
            short8 af[4], bf[4];
            #pragma unroll
            for (int mf = 0; mf < 4; ++mf) {
                int o = wm + mf * 16 + col;
                af[mf] = *(const short8*)&Ab[o * 64 + ((slot ^ (col & 7)) << 3)];
            }
            #pragma unroll
            for (int nf = 0; nf < 4; ++nf) {
                int pidx = pbase + (nf & 1) * 20 + (nf >> 1) * 60;
                bf[nf] = *(const short8*)&Bh[pidx * 64 + ((slot ^ (pidx & 7)) << 3)];
            }
            #pragma unroll
            for (int mf = 0; mf < 4; ++mf)
                #pragma unroll
                for (int nf = 0; nf < 4; ++nf)
                    acc[mf][nf] = __builtin_amdgcn_mfma_f32_16x16x32_bf16(af[mf], bf[nf], acc[mf][nf], 0, 0, 0);
        }

        __syncthreads();   // drains vmcnt -> At[buf^1] ready; all reads of At[buf] done
        buf ^= 1;
    }

    // ---- epilogue: + bias, store ----
    #pragma unroll
    for (int nf = 0; nf < 4; ++nf) {
        int pz2 = z0 + tzb0 + (nf >> 1);
        int py2 = y0 + tyb0 + (nf & 1) * 2;
        int p   = pz2 * (DIM * DIM) + py2 * DIM + x0 + twb;
        #pragma unroll
        for (int mf = 0; mf < 4; ++mf) {
            int ob = wm + mf * 16 + krow * 4;
            f32x4 a = acc[mf][nf];
            #pragma unroll
            for (int r = 0; r < 4; ++r) {
                int o = ob + r;
                out[(size_t)(b * COUT + o) * SP + p] = a[r] + lbias[o];
            }
        }
    }
}

// ===========================================================================
// FALLBACK PATH (round-2 kernels, used if ws_size < NEED_FAST)
// ===========================================================================

__global__ void build_wsb_kernel(const float* __restrict__ weight, float* __restrict__ ws) {
    const float* s1p = ws + WS_S1P;
    const float* km  = ws + WS_KM;
    unsigned short* WSB = (unsigned short*)(ws + WS_WSB);
    int idx = blockIdx.x * blockDim.x + threadIdx.x;
    if (idx >= NB * COUT * KTOT) return;
    int k = idx % KTOT;
    int o = (idx / KTOT) % COUT;
    int b = idx / (COUT * KTOT);
    int tau = k >> 6;
    int c   = k & 63;
    float wm = weight[(o * CIN + c) * TAPS + tau] * (1.f + km[b * (CIN * TAPS) + c * TAPS + tau]);
    float v  = wm * s1p[b * CIN + c];
    __hip_bfloat16 h = __float2bfloat16(v);
    WSB[idx] = *(unsigned short*)&h;
}

__global__ void build_wt_kernel(const float* __restrict__ weight, float* __restrict__ ws) {
    const float* sh = ws + WS_SH;
    const float* km = ws + WS_KM;
    float* WT = ws + WS_WT;
    int idx = blockIdx.x * blockDim.x + threadIdx.x;
    if (idx >= NB * COUT * TAPS) return;
    int tau = idx % TAPS;
    int o   = (idx / TAPS) % COUT;
    int b   = idx / (COUT * TAPS);
    float acc = 0.f;
    for (int c = 0; c < CIN; ++c) {
        float wm = weight[(o * CIN + c) * TAPS + tau] * (1.f + km[(b * CIN + c) * TAPS + tau]);
        acc += wm * sh[b * CIN + c];
    }
    WT[idx] = acc;
}

__global__ void build_wtf_kernel(float* __restrict__ ws) {
    int i = blockIdx.x * blockDim.x + threadIdx.x;
    if (i >= NB * COUT) return;
    const float* wt = ws + WS_WT + i * TAPS;
    float s = 0.f;
    #pragma unroll
    for (int t = 0; t < TAPS; ++t) s += wt[t];
    ws[WS_WTF + i] = s;
}

#define BN 128
#define NTILES (SP / BN)   // 864

__global__ __launch_bounds__(256) void conv_mfma_kernel(
    const float* __restrict__ x,
    const float* __restrict__ bias,
    const float* __restrict__ ws,
    float* __restrict__ out)
{
    const unsigned short* WSB = (const unsigned short*)(ws + WS_WSB);
    const float* WT  = ws + WS_WT;
    const float* WTF = ws + WS_WTF;

    __shared__ __attribute__((aligned(16))) unsigned short Atf[128 * 40];
    __shared__ __attribute__((aligned(16))) unsigned short Btf[128 * 40];
    __shared__ float WTl[128][28];
    __shared__ float lbias[128];

    int bid  = blockIdx.x;
    int tile = bid % NTILES;
    int b    = bid / NTILES;
    int p0   = tile * BN;

    int t    = threadIdx.x;
    int lane = t & 63;
    int wid  = t >> 6;
    int wm   = (wid >> 1) * 64;
    int wn   = (wid & 1) * 64;

    f32x4 acc[4][4] = {};

    int bn  = t & 127;
    int bch = t >> 7;
    int p   = p0 + bn;
    int wq  = p % DIM;
    int hq  = (p / DIM) % DIM;
    int dq  = p / (DIM * DIM);

    int am = t >> 1;
    int ak = (t & 1) * 16;

    const float* xb = x + (size_t)b * CIN * SP;
    const unsigned short* wsbB = WSB + (size_t)(b * COUT + am) * KTOT;

    for (int kk = 0; kk < 54; ++kk) {
        int tau   = kk >> 1;
        int chalf = (kk & 1) * 32;
        int dz = tau / 9 - 1;
        int dy = (tau / 3) % 3 - 1;
        int dx = tau % 3 - 1;

        {
            const u16x8* src = (const u16x8*)(wsbB + tau * 64 + chalf + ak);
            u16x8 a0 = src[0];
            u16x8 a1 = src[1];
            *(u16x8*)(&Atf[am * 40 + ak])     = a0;
            *(u16x8*)(&Atf[am * 40 + ak + 8]) = a1;
        }
        {
            bool valid = ((unsigned)(dq + dz) < (unsigned)DIM) &&
                         ((unsigned)(hq + dy) < (unsigned)DIM) &&
                         ((unsigned)(wq + dx) < (unsigned)DIM);
            int off = dz * (DIM * DIM) + dy * DIM + dx;
            unsigned short v16[16];
            if (valid) {
                const float* src = xb + (size_t)(chalf + bch * 16) * SP + p + off;
                #pragma unroll
                for (int i = 0; i < 16; ++i) {
                    __hip_bfloat16 h = __float2bfloat16(src[0]);
                    v16[i] = *(unsigned short*)&h;
                    src += SP;
                }
            } else {
                #pragma unroll
                for (int i = 0; i < 16; ++i) v16[i] = 0;
            }
            u16x8* dst = (u16x8*)(&Btf[bn * 40 + bch * 16]);
            u16x8 pk0, pk1;
            #pragma unroll
            for (int i = 0; i < 8; ++i) { pk0[i] = v16[i]; pk1[i] = v16[i + 8]; }
            dst[0] = pk0;
            dst[1] = pk1;
        }

        __syncthreads();

        short8 af[4], bf[4];
        int arow = lane & 15;
        int kofs = (lane >> 4) * 8;
        #pragma unroll
        for (int mf = 0; mf < 4; ++mf)
            af[mf] = *(const short8*)(&Atf[(wm + mf * 16 + arow) * 40 + kofs]);
        #pragma unroll
        for (int nf = 0; nf < 4; ++nf)
            bf[nf] = *(const short8*)(&Btf[(wn + nf * 16 + arow) * 40 + kofs]);
        #pragma unroll
        for (int mf = 0; mf < 4; ++mf)
            #pragma unroll
            for (int nf = 0; nf < 4; ++nf)
                acc[mf][nf] = __builtin_amdgcn_mfma_f32_16x16x32_bf16(af[mf], bf[nf], acc[mf][nf], 0, 0, 0);

        __syncthreads();
    }

    for (int i = t; i < 128 * 28; i += 256) {
        int o = i / 28, j = i - o * 28;
        WTl[o][j] = (j < 27) ? WT[(b * COUT + o) * TAPS + j] : WTF[b * COUT + o];
    }
    if (t < 128) lbias[t] = bias[t];
    __syncthreads();

    #pragma unroll
    for (int nf = 0; nf < 4; ++nf) {
        int n  = wn + nf * 16 + (lane & 15);
        int pc = p0 + n;
        int wq2 = pc % DIM;
        int hq2 = (pc / DIM) % DIM;
        int dq2 = pc / (DIM * DIM);
        bool interior = ((unsigned)(wq2 - 1) < (unsigned)(DIM - 2)) &&
                        ((unsigned)(hq2 - 1) < (unsigned)(DIM - 2)) &&
                        ((unsigned)(dq2 - 1) < (unsigned)(DIM - 2));
        bool mw[3] = { wq2 > 0, true, wq2 < DIM - 1 };
        bool mh[3] = { hq2 > 0, true, hq2 < DIM - 1 };
        bool md[3] = { dq2 > 0, true, dq2 < DIM - 1 };

        #pragma unroll
        for (int mf = 0; mf < 4; ++mf) {
            int ob = wm + mf * 16 + ((lane >> 4) << 2);
            f32x4 a = acc[mf][nf];
            #pragma unroll
            for (int r = 0; r < 4; ++r) {
                int o = ob + r;
                float v = a[r] + lbias[o];
                if (interior) {
                    v += WTl[o][27];
                } else {
                    const float* wt = WTl[o];
                    float s = 0.f;
                    #pragma unroll
                    for (int a3 = 0; a3 < 3; ++a3)
                        #pragma unroll
                        for (int b3 = 0; b3 < 3; ++b3)
                            #pragma unroll
                            for (int c3 = 0; c3 < 3; ++c3)
                                s += (md[a3] && mh[b3] && mw[c3]) ? wt[a3 * 9 + b3 * 3 + c3] : 0.f;
                    v += s;
                }
                out[(size_t)(b * COUT + o) * SP + pc] = v;
            }
        }
    }
}

// ---------------------------------------------------------------------------
extern "C" void kernel_launch(void* const* d_in, const int* in_sizes, int n_in,
                              void* d_out, int out_size, void* d_ws, size_t ws_size,
                              hipStream_t stream) {
    const float* x       = (const float*)d_in[0];
    const float* style   = (const float*)d_in[1];
    const float* weight  = (const float*)d_in[2];
    const float* bias    = (const float*)d_in[3];
    const float* w_scale = (const float*)d_in[4];
    const float* b_scale = (const float*)d_in[5];
    const float* w_shift = (const float*)d_in[6];
    const float* b_shift = (const float*)d_in[7];
    const float* w_kmod  = (const float*)d_in[8];
    const float* b_kmod  = (const float*)d_in[9];
    float* out = (float*)d_out;
    float* ws  = (float*)d_ws;

    {
        int waves = NB * (2 * CIN + CIN * TAPS);
        int blocks = (waves + 3) / 4;
        modparams_kernel<<<blocks, 256, 0, stream>>>(style, w_scale, b_scale,
                                                     w_shift, b_shift, w_kmod, b_kmod, ws);
    }

    if (ws_size >= NEED_FAST) {
        unsigned short* xpb  = (unsigned short*)((char*)d_ws + XPB_OFF);
        unsigned short* wsbf = (unsigned short*)((char*)d_ws + WSBF_OFF);
        {
            int n = NB * COUT * KTOT;
            build_wsbf_kernel<<<(n + 255) / 256, 256, 0, stream>>>(weight, ws, wsbf);
        }
        {
            int blocks = NB * 50 * 50;
            pad_kernel<<<blocks, 256, 0, stream>>>(x, ws, xpb);
        }
        {
            int blocks = NB * 864;
            conv_fast_kernel<<<blocks, 256, 0, stream>>>(xpb, wsbf, bias, out);
        }
    } else {
        {
            int n = NB * COUT * KTOT;
            build_wsb_kernel<<<(n + 255) / 256, 256, 0, stream>>>(weight, ws);
        }
        {
            int n = NB * COUT * TAPS;
            build_wt_kernel<<<(n + 255) / 256, 256, 0, stream>>>(weight, ws);
        }
        {
            int n = NB * COUT;
            build_wtf_kernel<<<(n + 255) / 256, 256, 0, stream>>>(ws);
        }
        {
            int blocks = NB * NTILES;
            conv_mfma_kernel<<<blocks, 256, 0, stream>>>(x, bias, ws, out);
        }
    }
}

// Round 4
// 331.341 us; speedup vs baseline: 53.4925x; 1.0615x over previous
//
#include <hip/hip_runtime.h>
#include <hip/hip_bf16.h>

// Problem constants
#define NB   4
#define CIN  64
#define COUT 128
#define SDIM 512
#define DIM  48
#define SP   (DIM*DIM*DIM)   // 110592
#define TAPS 27
#define KTOT (CIN*TAPS)      // 1728

// ---- small-param layout (float offsets at base of ws) ----
#define WS_S1P 0                         // [NB*CIN]       1+scale
#define WS_SH  (WS_S1P + NB*CIN)         // [NB*CIN]       shift
#define WS_KM  (WS_SH + NB*CIN)          // [NB*CIN*TAPS]  kmod
// ---- fast path byte offsets ----
#define XPB_OFF   32768ull                        // padded mod x (bf16 channel-last), 64 MB
#define XPB_BYTES (4ull*125000ull*64ull*2ull)     // 64,000,000
#define WSBF_OFF  (XPB_OFF + XPB_BYTES)
#define WSBF_BYTES ((size_t)NB*27*8*128*8*2)      // 1,769,472

typedef __attribute__((ext_vector_type(4))) float  f32x4;
typedef __attribute__((ext_vector_type(8))) short  short8;
typedef __attribute__((ext_vector_type(8))) unsigned short u16x8;

__device__ __forceinline__ void gld16(const void* g, void* l) {
    __builtin_amdgcn_global_load_lds(
        (const __attribute__((address_space(1))) void*)g,
        (__attribute__((address_space(3))) void*)l, 16, 0, 0);
}

// ---------------------------------------------------------------------------
// Kernel A: style dot products. One wave per row.
// rows: [0,64)=scale, [64,128)=shift, [128,1856)=kmod, per sample b.
// ---------------------------------------------------------------------------
__global__ void modparams_kernel(const float* __restrict__ style,
                                 const float* __restrict__ w_scale, const float* __restrict__ b_scale,
                                 const float* __restrict__ w_shift, const float* __restrict__ b_shift,
                                 const float* __restrict__ w_kmod,  const float* __restrict__ b_kmod,
                                 float* __restrict__ ws) {
    const int ROWS = 2 * CIN + CIN * TAPS;  // 1856
    int gwave = (blockIdx.x * blockDim.x + threadIdx.x) >> 6;
    int lane  = threadIdx.x & 63;
    if (gwave >= NB * ROWS) return;
    int b = gwave / ROWS;
    int r = gwave % ROWS;

    const float* srow = style + b * SDIM;
    const float* mrow;
    float bias, add = 0.f;
    float* dst;
    if (r < CIN) {
        mrow = w_scale + r * SDIM; bias = b_scale[r];
        dst = ws + WS_S1P + b * CIN + r; add = 1.f;          // store (1+scale)
    } else if (r < 2 * CIN) {
        int c = r - CIN;
        mrow = w_shift + c * SDIM; bias = b_shift[c];
        dst = ws + WS_SH + b * CIN + c;
    } else {
        int t = r - 2 * CIN;
        mrow = w_kmod + t * SDIM; bias = b_kmod[t];
        dst = ws + WS_KM + b * (CIN * TAPS) + t;
    }

    float acc = 0.f;
    for (int k = lane; k < SDIM; k += 64) acc += srow[k] * mrow[k];
    #pragma unroll
    for (int off = 32; off; off >>= 1) acc += __shfl_down(acc, off);
    if (lane == 0) *dst = acc + bias + add;
}

// ---------------------------------------------------------------------------
// WSBF2[(((b*27+tau)*8 + s)*128 + o)*8 + j] = bf16(weight[o, c=s*8+j, tau] *
//                                                  (1 + kmod[b, c, tau]))
// Layout makes conv A-staging a LINEAR gld16 stream and af reads conflict-free.
// ---------------------------------------------------------------------------
__global__ void build_wsbf2_kernel(const float* __restrict__ weight, const float* __restrict__ ws,
                                   unsigned short* __restrict__ wsbf) {
    int d = blockIdx.x * blockDim.x + threadIdx.x;
    if (d >= NB * 27 * 8 * 128 * 8) return;
    int j   = d & 7;
    int o   = (d >> 3) & 127;
    int s   = (d >> 10) & 7;
    int rem = d >> 13;
    int tau = rem % 27;
    int b   = rem / 27;
    int c   = s * 8 + j;
    float wm = weight[(o * CIN + c) * TAPS + tau] * (1.f + ws[WS_KM + b * KTOT + c * TAPS + tau]);
    __hip_bfloat16 h = __float2bfloat16(wm);
    wsbf[d] = *(unsigned short*)&h;
}

// ---------------------------------------------------------------------------
// Pad + modulate + transpose to channel-last bf16: xpb[b][pz][py][px][c]
// One block per (b, pz, py) padded row; 50 px x 64 c written coalesced.
// ---------------------------------------------------------------------------
__global__ __launch_bounds__(256) void pad_kernel(const float* __restrict__ x,
                                                  const float* __restrict__ ws,
                                                  unsigned short* __restrict__ xpb) {
    __shared__ unsigned short lxm[48 * 72];   // [w][c], row stride 144B (16B-aligned)
    int bid = blockIdx.x;
    int py = bid % 50;
    int pz = (bid / 50) % 50;
    int b  = bid / 2500;
    int t = threadIdx.x;
    bool interior = (pz >= 1 && pz <= 48 && py >= 1 && py <= 48);
    if (interior) {
        int z = pz - 1, y = py - 1;
        const float* xr = x + (size_t)b * CIN * SP + (size_t)z * (DIM*DIM) + y * DIM;
        for (int i = t; i < 3072; i += 256) {
            int c = i / 48, w = i % 48;
            float v = xr[(size_t)c * SP + w];
            float m = v * ws[WS_S1P + b * CIN + c] + ws[WS_SH + b * CIN + c];
            __hip_bfloat16 h = __float2bfloat16(m);
            lxm[w * 72 + c] = *(unsigned short*)&h;
        }
    }
    __syncthreads();
    unsigned short* dst = xpb + (size_t)b * 8000000ull + ((size_t)pz * 2500 + py * 50) * 64;
    for (int i8 = t; i8 < 400; i8 += 256) {
        int w  = i8 >> 3;          // padded px
        int c8 = (i8 & 7) * 8;
        u16x8 v = {};
        if (interior && w >= 1 && w <= 48)
            v = *(const u16x8*)&lxm[(w - 1) * 72 + c8];
        *(u16x8*)(dst + i8 * 8) = v;
    }
}

// ---------------------------------------------------------------------------
// Conv: block = 128 couts x 512 positions (8z x 8y x 8x box), 8 waves.
// Wave w owns z-plane w: full M=128 (mf=8), 64 N-positions (nf=4).
// Bh = 10x10x10 halo x 64c bf16 (128,000 B) staged once, XOR-swizzled.
// At = per-tap [slot(8)][o(128)] 16B-chunk weights, double-buffered (32,768 B).
// ---------------------------------------------------------------------------
__global__ __launch_bounds__(512, 2) void conv_fast2_kernel(
    const unsigned short* __restrict__ xpb,
    const unsigned short* __restrict__ wsbf,
    const float* __restrict__ bias,
    float* __restrict__ out)
{
    __shared__ unsigned short Bh[1000 * 64];   // 128,000 B
    __shared__ unsigned short At[2][8192];     // 2 x 16,384 B

    const int t    = threadIdx.x;
    const int lane = t & 63;
    const int wz   = t >> 6;        // wave id == z-offset 0..7

    int bid  = blockIdx.x;
    int tile = bid % 216;
    int b    = bid / 216;
    int tx = tile % 6;
    int ty = (tile / 6) % 6;
    int tz = tile / 36;
    int x0 = tx * 8, y0 = ty * 8, z0 = tz * 8;

    const unsigned short* xb = xpb + (size_t)b * 8000000ull;
    const unsigned short* wb = wsbf + (size_t)b * (27 * 8 * 128 * 8);

    // ---- stage B halo once (source-swizzled so linear LDS == swizzled layout)
    for (int it = 0; it < 16; ++it) {
        int i = it * 512 + t;
        if (i < 8000) {
            int pidx = i >> 3;
            int slot = i & 7;
            int hx = pidx % 10;
            int hy = (pidx / 10) % 10;
            int hz = pidx / 100;
            int srcslot = slot ^ (pidx & 7);
            const unsigned short* g = xb
                + ((size_t)((z0 + hz) * 2500 + (y0 + hy) * 50 + (x0 + hx))) * 64
                + srcslot * 8;
            gld16(g, &Bh[i * 8]);
        }
    }
    // ---- stage A tap 0 (linear) ----
    gld16(wb + (size_t)t * 8,         &At[0][t * 8]);
    gld16(wb + (size_t)(512 + t) * 8, &At[0][(512 + t) * 8]);
    __syncthreads();

    const int col  = lane & 15;
    const int krow = lane >> 4;   // 0..3
    const int cy   = col >> 3;    // 0..1
    const int cx   = col & 7;     // 0..7

    f32x4 acc[8][4] = {};
    int buf = 0;

    for (int tap = 0; tap < 27; ++tap) {
        // prefetch A for next tap (linear stream)
        if (tap < 26) {
            const unsigned short* wsrc = wb + (size_t)(tap + 1) * 8192;
            gld16(wsrc + t * 8,         &At[buf ^ 1][t * 8]);
            gld16(wsrc + (512 + t) * 8, &At[buf ^ 1][(512 + t) * 8]);
        }
        int kd = tap / 9;
        int r9 = tap - kd * 9;
        int kh = r9 / 3;
        int kw = r9 - kh * 3;
        int pb_ = (wz + kd) * 100 + (cy + kh) * 10 + cx + kw;

        const unsigned short* Ab = At[buf];
        #pragma unroll
        for (int ch = 0; ch < 2; ++ch) {
            int slot = ch * 4 + krow;
            short8 af[8], bf[4];
            #pragma unroll
            for (int mf = 0; mf < 8; ++mf)
                af[mf] = *(const short8*)&Ab[(slot * 128 + mf * 16 + col) * 8];
            #pragma unroll
            for (int nf = 0; nf < 4; ++nf) {
                int pidx = pb_ + nf * 20;
                bf[nf] = *(const short8*)&Bh[pidx * 64 + ((slot ^ (pidx & 7)) * 8)];
            }
            #pragma unroll
            for (int mf = 0; mf < 8; ++mf)
                #pragma unroll
                for (int nf = 0; nf < 4; ++nf)
                    acc[mf][nf] = __builtin_amdgcn_mfma_f32_16x16x32_bf16(af[mf], bf[nf], acc[mf][nf], 0, 0, 0);
        }

        __syncthreads();   // drains vmcnt -> At[buf^1] ready; reads of At[buf] done
        buf ^= 1;
    }

    // ---- epilogue: + bias, store ----
    int z = z0 + wz;
    #pragma unroll
    for (int mf = 0; mf < 8; ++mf) {
        f32x4 bv = *(const f32x4*)&bias[mf * 16 + krow * 4];
        #pragma unroll
        for (int nf = 0; nf < 4; ++nf) {
            int y = y0 + nf * 2 + cy;
            int x = x0 + cx;
            size_t pbase = (size_t)z * (DIM * DIM) + (size_t)y * DIM + x;
            f32x4 a = acc[mf][nf];
            #pragma unroll
            for (int r = 0; r < 4; ++r) {
                int o = mf * 16 + krow * 4 + r;
                out[(size_t)(b * COUT + o) * SP + pbase] = a[r] + bv[r];
            }
        }
    }
}

// ---------------------------------------------------------------------------
extern "C" void kernel_launch(void* const* d_in, const int* in_sizes, int n_in,
                              void* d_out, int out_size, void* d_ws, size_t ws_size,
                              hipStream_t stream) {
    const float* x       = (const float*)d_in[0];
    const float* style   = (const float*)d_in[1];
    const float* weight  = (const float*)d_in[2];
    const float* bias    = (const float*)d_in[3];
    const float* w_scale = (const float*)d_in[4];
    const float* b_scale = (const float*)d_in[5];
    const float* w_shift = (const float*)d_in[6];
    const float* b_shift = (const float*)d_in[7];
    const float* w_kmod  = (const float*)d_in[8];
    const float* b_kmod  = (const float*)d_in[9];
    float* out = (float*)d_out;
    float* ws  = (float*)d_ws;

    unsigned short* xpb  = (unsigned short*)((char*)d_ws + XPB_OFF);
    unsigned short* wsbf = (unsigned short*)((char*)d_ws + WSBF_OFF);

    {
        int waves = NB * (2 * CIN + CIN * TAPS);
        int blocks = (waves + 3) / 4;
        modparams_kernel<<<blocks, 256, 0, stream>>>(style, w_scale, b_scale,
                                                     w_shift, b_shift, w_kmod, b_kmod, ws);
    }
    {
        int n = NB * 27 * 8 * 128 * 8;
        build_wsbf2_kernel<<<(n + 255) / 256, 256, 0, stream>>>(weight, ws, wsbf);
    }
    {
        int blocks = NB * 50 * 50;
        pad_kernel<<<blocks, 256, 0, stream>>>(x, ws, xpb);
    }
    {
        int blocks = NB * 216;
        conv_fast2_kernel<<<blocks, 512, 0, stream>>>(xpb, wsbf, bias, out);
    }
}